// Round 3
// baseline (412.774 us; speedup 1.0000x reference)
//
#include <hip/hip_runtime.h>

#define ROW_F4 192   // 768 floats = 192 float4 per output row
#define CHUNK  16    // rows per wave
#define ROWS_PER_BLOCK (4 * CHUNK)   // 4 waves/block

typedef float v4f __attribute__((ext_vector_type(4)));

// One wave = 16 consecutive rows. Lane layout per row (192 float4 slots):
//   slot = k*64 + lane, k in {0,1,2}; lane<32 -> segment 2k, lane>=32 -> 2k+1.
// k=0 (price|size) is row-invariant -> held in a register.
// k=1 (exchange%3 | pair%7) and k=2 (level%15 | time%31) use incremental
// per-lane row counters instead of per-row magic-divide mods.
//
// Templated on NT for a within-round A/B, dispatched as NT|plain|NT|plain
// quarters so each store path is measured twice at different stream
// positions (controls for cold-TLB / poison-overlap on dispatch 1).
template <bool NT>
__global__ __launch_bounds__(256) void smart_embedding_kernel(
    const v4f* __restrict__ price_w,
    const v4f* __restrict__ size_w,
    const v4f* __restrict__ exchange_w,   // each table row = 32 float4
    const v4f* __restrict__ pair_w,
    const v4f* __restrict__ level_w,
    const v4f* __restrict__ time_w,
    v4f* __restrict__ out,
    int row0,        // first row this dispatch owns
    int rows_end)    // one past last row
{
    const int tid  = threadIdx.x;
    const int wave = tid >> 6;
    const int lane = tid & 63;
    const int off  = lane & 31;          // float4 slot within a 128-float segment
    const bool hi  = lane >= 32;

    int r0 = row0 + (blockIdx.x * 4 + wave) * CHUNK;
    if (r0 >= rows_end) return;
    const int rend = (r0 + CHUNK < rows_end) ? r0 + CHUNK : rows_end;

    // Row-invariant segment (k=0): price for lo half, size for hi half.
    const v4f v0 = hi ? size_w[off] : price_w[off];

    // Per-lane table base + period for k=1, k=2.
    const v4f* base1 = hi ? pair_w : exchange_w;
    const v4f* base2 = hi ? time_w : level_w;
    const int p1 = hi ? 7  : 3;
    const int p2 = hi ? 31 : 15;

    int m1 = r0 % p1;                    // one-time magic-divide, then incremental
    int m2 = r0 % p2;

    v4f* orow = out + (size_t)r0 * ROW_F4 + lane;

#pragma unroll 4
    for (int r = r0; r < rend; ++r) {
        v4f v1 = base1[m1 * 32 + off];   // L1-resident (tables total ~30 KB)
        v4f v2 = base2[m2 * 32 + off];
        if constexpr (NT) {
            __builtin_nontemporal_store(v0, orow);
            __builtin_nontemporal_store(v1, orow + 64);   // imm offset 1024 B
            __builtin_nontemporal_store(v2, orow + 128);  // imm offset 2048 B
        } else {
            orow[0]   = v0;              // plain stores: allocate in L2, drain async
            orow[64]  = v1;
            orow[128] = v2;
        }
        orow += ROW_F4;
        m1 = (m1 + 1 == p1) ? 0 : m1 + 1;
        m2 = (m2 + 1 == p2) ? 0 : m2 + 1;
    }
}

static inline void launch_seg(bool nt, const v4f* price_w, const v4f* size_w,
                              const v4f* exchange_w, const v4f* pair_w,
                              const v4f* level_w, const v4f* time_w,
                              v4f* out, int row0, int rows_end, hipStream_t stream) {
    if (rows_end <= row0) return;
    const int blocks = (rows_end - row0 + ROWS_PER_BLOCK - 1) / ROWS_PER_BLOCK;
    if (nt)
        smart_embedding_kernel<true><<<blocks, 256, 0, stream>>>(
            price_w, size_w, exchange_w, pair_w, level_w, time_w, out, row0, rows_end);
    else
        smart_embedding_kernel<false><<<blocks, 256, 0, stream>>>(
            price_w, size_w, exchange_w, pair_w, level_w, time_w, out, row0, rows_end);
}

extern "C" void kernel_launch(void* const* d_in, const int* in_sizes, int n_in,
                              void* d_out, int out_size, void* d_ws, size_t ws_size,
                              hipStream_t stream) {
    const v4f* price_w    = (const v4f*)d_in[0];
    const v4f* size_w     = (const v4f*)d_in[1];
    const v4f* exchange_w = (const v4f*)d_in[2];
    const v4f* pair_w     = (const v4f*)d_in[3];
    const v4f* level_w    = (const v4f*)d_in[4];
    const v4f* time_w     = (const v4f*)d_in[5];
    v4f* out = (v4f*)d_out;

    const int rows = out_size / 768;                       // = num_features

    // Four quarter-dispatches: NT, plain, NT, plain (position-controlled A/B).
    int q = (rows / 4) & ~(ROWS_PER_BLOCK - 1);
    int b0 = q, b1 = 2 * q, b2 = 3 * q;

    launch_seg(true,  price_w, size_w, exchange_w, pair_w, level_w, time_w, out, 0,   b0,   stream);
    launch_seg(false, price_w, size_w, exchange_w, pair_w, level_w, time_w, out, b0,  b1,   stream);
    launch_seg(true,  price_w, size_w, exchange_w, pair_w, level_w, time_w, out, b1,  b2,   stream);
    launch_seg(false, price_w, size_w, exchange_w, pair_w, level_w, time_w, out, b2,  rows, stream);
}

// Round 9
// 406.972 us; speedup vs baseline: 1.0143x; 1.0143x over previous
//
#include <hip/hip_runtime.h>

#define ROW_F4 192    // 768 floats = 192 float4 per output row
#define NCLS   3255   // lcm(3,7,15,31): rows in one class share ALL table indices

typedef float v4f __attribute__((ext_vector_type(4)));

// CRT restructure: wave w owns residue class w (mod 3255). Every row r ≡ w
// (mod 3255) uses the same exchange/pair/level/time rows, so all table data
// is loaded ONCE per wave into registers and the steady-state loop is pure
// stores — no loads, no vmcnt coupling, no per-row index math.
//
// Lane layout per row (192 float4 slots): slot = k*64 + lane, k in {0,1,2};
// lane<32 -> segment 2k (price|exchange|level), lane>=32 -> 2k+1
// (size|pair|time). Each store instruction = 64 lanes x 16 B = 1 KB
// contiguous; the 3 stores cover the full 3 KB row.
__global__ __launch_bounds__(256) void smart_embedding_kernel(
    const v4f* __restrict__ price_w,
    const v4f* __restrict__ size_w,
    const v4f* __restrict__ exchange_w,   // each table row = 32 float4
    const v4f* __restrict__ pair_w,
    const v4f* __restrict__ level_w,
    const v4f* __restrict__ time_w,
    v4f* __restrict__ out,
    int rows)
{
    const int tid  = threadIdx.x;
    const int wave = tid >> 6;
    const int lane = tid & 63;
    const int off  = lane & 31;          // float4 slot within a 128-float segment
    const bool hi  = lane >= 32;

    const int cls = blockIdx.x * 4 + wave;   // residue class mod NCLS
    if (cls >= NCLS) return;

    // One-time per-wave table reads (divergent-base gather, L1-resident).
    const v4f v0 = hi ? size_w[off] : price_w[off];
    const int m1 = hi ? cls % 7  : cls % 3;    // 3|3255, 7|3255
    const int m2 = hi ? cls % 31 : cls % 15;   // 15|3255, 31|3255
    const v4f v1 = (hi ? pair_w     : exchange_w)[m1 * 32 + off];
    const v4f v2 = (hi ? time_w     : level_w  )[m2 * 32 + off];

    v4f* orow = out + (size_t)cls * ROW_F4 + lane;
    const size_t step = (size_t)NCLS * ROW_F4;   // 9.54 MB between owned rows

    // ~40 iterations; 3 independent coalesced 1 KB stores each, zero loads.
#pragma unroll 4
    for (int r = cls; r < rows; r += NCLS) {
        orow[0]   = v0;
        orow[64]  = v1;    // imm offset 1024 B
        orow[128] = v2;    // imm offset 2048 B
        orow += step;
    }
}

extern "C" void kernel_launch(void* const* d_in, const int* in_sizes, int n_in,
                              void* d_out, int out_size, void* d_ws, size_t ws_size,
                              hipStream_t stream) {
    const v4f* price_w    = (const v4f*)d_in[0];
    const v4f* size_w     = (const v4f*)d_in[1];
    const v4f* exchange_w = (const v4f*)d_in[2];
    const v4f* pair_w     = (const v4f*)d_in[3];
    const v4f* level_w    = (const v4f*)d_in[4];
    const v4f* time_w     = (const v4f*)d_in[5];
    v4f* out = (v4f*)d_out;

    const int rows = out_size / 768;             // = num_features
    const int blocks = (NCLS + 3) / 4;           // 814 blocks x 4 waves covers 3255 classes

    smart_embedding_kernel<<<blocks, 256, 0, stream>>>(
        price_w, size_w, exchange_w, pair_w, level_w, time_w, out, rows);
}